// Round 7
// baseline (131.839 us; speedup 1.0000x reference)
//
#include <hip/hip_runtime.h>
#include <hip/hip_bf16.h>
#include <math.h>

#define N 8192
#define D 64
#define INVT 20.0f
#define EPS 1e-6f
// sqrt(20/ln2): gram(Z) = 20*log2(e)*cos, so exp2(gram) = e^{20 cos}
#define ZSCALE 5.3715835f

typedef __attribute__((ext_vector_type(8))) short bf16x8;
typedef __attribute__((ext_vector_type(4))) float f32x4;

#if __has_builtin(__builtin_amdgcn_exp2f)
#define EXP2F(x) __builtin_amdgcn_exp2f(x)
#else
#define EXP2F(x) exp2f(x)
#endif

// Z layout (fragment order): G-row R, element l stored at bf16 index
//   ( (R>>4)*128 + (l>>5)*64 + ((l>>3)&3)*16 + (R&15) )*8 + (l&7)
// MFMA fragment load for 16-row group g, K-chunk kc = contiguous 1 KB wave
// load Zf[g*128 + kc*64 + lane].
//
// HISTORY (keep):
//  - R9/R12: (256,5) spills. (256,4) is the occupancy ceiling.
//  - R10: __threadfence in all blocks -> L2 thrash, 5x slower.
//  - R11 (93.1us): 1 tile/block. R13 (91.8us): 2 ranks/block + prefetch.
//  - R14-R16: strip-mining / big unrolls fight compiler (scratch, spill).
//  - R17/R18 (107/101us): store+gather round-trip WORSE than atomics.
//  - R19 (98.2us): af1-reuse+swizzle dropped tiles FETCH 89->11MB but dur
//    stayed 42.8us; VALUBusy 41/Mfma 15/Occ 30 -> ~60% stall at 22% HBM.
//    Fragment traffic was never the stall; the LDS-transpose+barrier+merge
//    chain locks 4 waves in lockstep -> no cross-wave latency hiding.
//  - R20 (this): wave-independent epilogue. Row sums reduced in-register
//    (4x shfl_xor per component over the 16-lane col group), lanes ln<4
//    atomic one 64B line per stripe. Col sums via shfl 16/32 + per-lane
//    atomic. ZERO __syncthreads, ZERO LDS. Row atomics -> partR, col ->
//    partC (separate arrays, merged in loss) to halve per-line contention.
//    Cost: 2x atomics (4.1M) -- fire-and-forget, overlaps compute.

__device__ __forceinline__ void unrank(int t, int& bi, int& bj) {
    int b = (int)((257.0f - sqrtf(66049.0f - 8.0f * (float)t)) * 0.5f);
    while (b * (257 - b) / 2 > t) --b;
    while ((b + 1) * (256 - b) / 2 <= t) ++b;
    bi = b;
    bj = b + (t - b * (257 - b) / 2);
}

// ---------------- Kernel 1: normalize -> scaled bf16 Z (fragment order),
//                  zero partR/partC (4N floats) / lacc / cnt ----------------
__global__ __launch_bounds__(256) void prep_kernel(
    const float* __restrict__ A, const float* __restrict__ P,
    __hip_bfloat16* __restrict__ Zn, float* __restrict__ diag20,
    float* __restrict__ part, float* __restrict__ lacc, unsigned* __restrict__ cnt) {
    if (blockIdx.x < 128) part[blockIdx.x * 256 + threadIdx.x] = 0.0f;
    else if (blockIdx.x == 128 && threadIdx.x == 0) { *lacc = 0.0f; *cnt = 0u; }

    const int lane = threadIdx.x & 63;   // element index l
    const int w    = threadIdx.x >> 6;
    const int r    = blockIdx.x * 4 + w; // A/P row
    const int u    = lane >> 3, sub = lane & 7;
    const int upos = (u >> 2) * 64 + (u & 3) * 16;   // kc*64 + q*16

    float a = A[r * D + lane];
    float p = P[r * D + lane];
    float sa = a * a, sp = p * p, dp = a * p;
    #pragma unroll
    for (int off = 1; off < 64; off <<= 1) {
        sa += __shfl_xor(sa, off, 64);
        sp += __shfl_xor(sp, off, 64);
        dp += __shfl_xor(dp, off, 64);
    }
    float na  = sqrtf(sa);
    float npn = sqrtf(sp);
    {   // A-row R = r
        int g = r >> 4, l2 = r & 15;
        Zn[(g * 128 + upos + l2) * 8 + sub] = __float2bfloat16(a * (ZSCALE / na));
    }
    {   // P-row R = N + r
        int R = N + r; int g = R >> 4, l2 = R & 15;
        Zn[(g * 128 + upos + l2) * 8 + sub] = __float2bfloat16(p * (ZSCALE / npn));
    }
    if (lane == 0)
        diag20[r] = (dp / fmaxf(na * npn, EPS)) * INVT;
}

// ---------------- Kernel 2: two triangular ranks per block, barrier-free ----
__global__ __launch_bounds__(256, 4) void tiles_kernel(
    const __hip_bfloat16* __restrict__ Zn,
    float* __restrict__ partR, float* __restrict__ partC) {
    const int tid = threadIdx.x;
    const int lane = tid & 63, w = tid >> 6;
    const int wr = w >> 1, wc = w & 1;
    const int ln = lane & 15, q = lane >> 4;
    const bf16x8* Zf = (const bf16x8*)Zn;

    // XCD-aware swizzle: 4128 blocks = 8 XCDs x 516; default XCD = b%8.
    // Contiguous wgid band per XCD -> contiguous bi band -> part-line and
    // fragment L2 locality (validated: FETCH 89->11MB in R19).
    const int b = (int)blockIdx.x;
    const int wgid = (b & 7) * 516 + (b >> 3);
    const int t0 = 2 * wgid;
    const int t1 = t0 + 1;
    int bi0, bj0, bi1, bj1;
    unrank(t0, bi0, bj0);
    unrank(t1, bi1, bj1);

    const f32x4 zero = {0.0f, 0.0f, 0.0f, 0.0f};

    // ---------------- tile 0: load fragments ----------------
    bf16x8 af0[4][2], bv0[4][2];
    #pragma unroll
    for (int ii = 0; ii < 4; ++ii) {
        int ga = bi0 * 8 + wr * 4 + ii;
        int gb = bj0 * 8 + wc * 4 + ii;
        #pragma unroll
        for (int kc = 0; kc < 2; ++kc) {
            af0[ii][kc] = Zf[ga * 128 + kc * 64 + lane];
            bv0[ii][kc] = Zf[gb * 128 + kc * 64 + lane];
        }
    }

    // ---------------- tile 0: stripes (MFMA + exp + in-reg row flush) -------
    const bool dwave0 = (bi0 == bj0) && (wr == wc);
    float csum[4] = {0.0f, 0.0f, 0.0f, 0.0f};
    #pragma unroll
    for (int ii = 0; ii < 4; ++ii) {
        f32x4 acc[4];
        #pragma unroll
        for (int jj = 0; jj < 4; ++jj)
            acc[jj] = __builtin_amdgcn_mfma_f32_16x16x32_bf16(
                af0[ii][0], bv0[jj][0], zero, 0, 0, 0);
        #pragma unroll
        for (int jj = 0; jj < 4; ++jj)
            acc[jj] = __builtin_amdgcn_mfma_f32_16x16x32_bf16(
                af0[ii][1], bv0[jj][1], acc[jj], 0, 0, 0);

        f32x4 rsum_ii = {};
        #pragma unroll
        for (int jj = 0; jj < 4; ++jj) {
            f32x4 e;
            #pragma unroll
            for (int r = 0; r < 4; ++r) e[r] = EXP2F(acc[jj][r]);
            if (dwave0 && (ii == jj)) {
                #pragma unroll
                for (int r = 0; r < 4; ++r)
                    if (ln == q * 4 + r) e[r] = 0.0f;
            }
            rsum_ii += e;
            csum[jj] += (e[0] + e[1]) + (e[2] + e[3]);
        }
        // in-register row reduce over the 16-lane col group
        #pragma unroll
        for (int c = 0; c < 4; ++c) {
            rsum_ii[c] += __shfl_xor(rsum_ii[c], 1, 64);
            rsum_ii[c] += __shfl_xor(rsum_ii[c], 2, 64);
            rsum_ii[c] += __shfl_xor(rsum_ii[c], 4, 64);
            rsum_ii[c] += __shfl_xor(rsum_ii[c], 8, 64);
        }
        if (ln < 4) {
            float rv = (ln == 0) ? rsum_ii[0] : (ln == 1) ? rsum_ii[1]
                     : (ln == 2) ? rsum_ii[2] : rsum_ii[3];
            // rows q*4+0..3 of group bi0*8+wr*4+ii; 16 lanes -> one 64B line
            atomicAdd(partR + bi0 * 128 + wr * 64 + ii * 16 + q * 4 + ln, rv);
        }
    }

    // ---------------- prefetch tile 1 fragments ----------------
    // af reused when the pair stays in the same row block (4064/4128 pairs).
    bf16x8 af1[4][2], bv1[4][2];
    #pragma unroll
    for (int ii = 0; ii < 4; ++ii) {
        int gb = bj1 * 8 + wc * 4 + ii;
        #pragma unroll
        for (int kc = 0; kc < 2; ++kc)
            bv1[ii][kc] = Zf[gb * 128 + kc * 64 + lane];
    }
    if (bi1 == bi0) {
        #pragma unroll
        for (int ii = 0; ii < 4; ++ii) {
            af1[ii][0] = af0[ii][0];
            af1[ii][1] = af0[ii][1];
        }
    } else {
        #pragma unroll
        for (int ii = 0; ii < 4; ++ii) {
            int ga = bi1 * 8 + wr * 4 + ii;
            #pragma unroll
            for (int kc = 0; kc < 2; ++kc)
                af1[ii][kc] = Zf[ga * 128 + kc * 64 + lane];
        }
    }

    // ---------------- tile 0: col flush (shfl + per-lane atomic) ------------
    if (bi0 != bj0) {
        float cs0 = csum[0], cs1 = csum[1], cs2 = csum[2], cs3 = csum[3];
        cs0 += __shfl_xor(cs0, 16, 64); cs0 += __shfl_xor(cs0, 32, 64);
        cs1 += __shfl_xor(cs1, 16, 64); cs1 += __shfl_xor(cs1, 32, 64);
        cs2 += __shfl_xor(cs2, 16, 64); cs2 += __shfl_xor(cs2, 32, 64);
        cs3 += __shfl_xor(cs3, 16, 64); cs3 += __shfl_xor(cs3, 32, 64);
        float cval = (q == 0) ? cs0 : (q == 1) ? cs1 : (q == 2) ? cs2 : cs3;
        // col = bj0*128 + wc*64 + q*16 + ln = bj0*128 + wc*64 + lane
        atomicAdd(partC + bj0 * 128 + wc * 64 + lane, cval);
    }

    // ---------------- tile 1: stripes (MFMA + exp + in-reg row flush) -------
    const bool dwave1 = (bi1 == bj1) && (wr == wc);
    float csumB[4] = {0.0f, 0.0f, 0.0f, 0.0f};
    #pragma unroll
    for (int ii = 0; ii < 4; ++ii) {
        f32x4 acc[4];
        #pragma unroll
        for (int jj = 0; jj < 4; ++jj)
            acc[jj] = __builtin_amdgcn_mfma_f32_16x16x32_bf16(
                af1[ii][0], bv1[jj][0], zero, 0, 0, 0);
        #pragma unroll
        for (int jj = 0; jj < 4; ++jj)
            acc[jj] = __builtin_amdgcn_mfma_f32_16x16x32_bf16(
                af1[ii][1], bv1[jj][1], acc[jj], 0, 0, 0);

        f32x4 rsum_ii = {};
        #pragma unroll
        for (int jj = 0; jj < 4; ++jj) {
            f32x4 e;
            #pragma unroll
            for (int r = 0; r < 4; ++r) e[r] = EXP2F(acc[jj][r]);
            if (dwave1 && (ii == jj)) {
                #pragma unroll
                for (int r = 0; r < 4; ++r)
                    if (ln == q * 4 + r) e[r] = 0.0f;
            }
            rsum_ii += e;
            csumB[jj] += (e[0] + e[1]) + (e[2] + e[3]);
        }
        #pragma unroll
        for (int c = 0; c < 4; ++c) {
            rsum_ii[c] += __shfl_xor(rsum_ii[c], 1, 64);
            rsum_ii[c] += __shfl_xor(rsum_ii[c], 2, 64);
            rsum_ii[c] += __shfl_xor(rsum_ii[c], 4, 64);
            rsum_ii[c] += __shfl_xor(rsum_ii[c], 8, 64);
        }
        if (ln < 4) {
            float rv = (ln == 0) ? rsum_ii[0] : (ln == 1) ? rsum_ii[1]
                     : (ln == 2) ? rsum_ii[2] : rsum_ii[3];
            atomicAdd(partR + bi1 * 128 + wr * 64 + ii * 16 + q * 4 + ln, rv);
        }
    }

    // ---------------- tile 1: col flush ----------------
    if (bi1 != bj1) {
        float cs0 = csumB[0], cs1 = csumB[1], cs2 = csumB[2], cs3 = csumB[3];
        cs0 += __shfl_xor(cs0, 16, 64); cs0 += __shfl_xor(cs0, 32, 64);
        cs1 += __shfl_xor(cs1, 16, 64); cs1 += __shfl_xor(cs1, 32, 64);
        cs2 += __shfl_xor(cs2, 16, 64); cs2 += __shfl_xor(cs2, 32, 64);
        cs3 += __shfl_xor(cs3, 16, 64); cs3 += __shfl_xor(cs3, 32, 64);
        float cval = (q == 0) ? cs0 : (q == 1) ? cs1 : (q == 2) ? cs2 : cs3;
        atomicAdd(partC + bj1 * 128 + wc * 64 + lane, cval);
    }
}

// ---------------- Kernel 3: per-row loss + reduce + last-block finalize ------
__global__ __launch_bounds__(256) void loss_kernel(
    const float* __restrict__ partR, const float* __restrict__ partC,
    const float* __restrict__ diag20,
    float* __restrict__ lacc, unsigned* __restrict__ cnt, float* __restrict__ out) {
    int i = blockIdx.x * 256 + threadIdx.x;
    float v = logf((partR[i] + partC[i]) + (partR[N + i] + partC[N + i]))
              - diag20[i];
    #pragma unroll
    for (int off = 32; off > 0; off >>= 1) v += __shfl_down(v, off, 64);
    __shared__ float wsm[4];
    int lane = threadIdx.x & 63, wv = threadIdx.x >> 6;
    if (lane == 0) wsm[wv] = v;
    __syncthreads();
    if (threadIdx.x == 0) {
        atomicAdd(lacc, wsm[0] + wsm[1] + wsm[2] + wsm[3]);
        __threadfence();
        unsigned old = atomicAdd(cnt, 1u);
        if (old == (N / 256 - 1)) {
            float tot = atomicAdd(lacc, 0.0f);
            out[0] = tot * (1.0f / (float)N);
        }
    }
}

// ---------------- launch ----------------
extern "C" void kernel_launch(void* const* d_in, const int* in_sizes, int n_in,
                              void* d_out, int out_size, void* d_ws, size_t ws_size,
                              hipStream_t stream) {
    const float* A = (const float*)d_in[0];
    const float* P = (const float*)d_in[1];

    __hip_bfloat16* Zn = (__hip_bfloat16*)d_ws;                 // 2N*64 bf16 = 2 MiB
    float* diag20 = (float*)((char*)d_ws + 2u * N * D * sizeof(__hip_bfloat16));
    float* partR  = diag20 + N;          // 2N floats (row sums)
    float* partC  = partR + 2 * N;       // 2N floats (col sums)
    float* lacc   = partC + 2 * N;
    unsigned* cnt = (unsigned*)(lacc + 1);

    prep_kernel<<<N / 4, 256, 0, stream>>>(A, P, Zn, diag20, partR, lacc, cnt);

    const int nblocks = 128 * 129 / 4;   // 4128 blocks, 2 triangular ranks each
    tiles_kernel<<<nblocks, 256, 0, stream>>>(Zn, partR, partC);

    loss_kernel<<<N / 256, 256, 0, stream>>>(partR, partC, diag20, lacc, cnt,
                                             (float*)d_out);
}

// Round 8
// 97.812 us; speedup vs baseline: 1.3479x; 1.3479x over previous
//
#include <hip/hip_runtime.h>
#include <hip/hip_bf16.h>
#include <math.h>

#define N 8192
#define D 64
#define INVT 20.0f
#define EPS 1e-6f
// sqrt(20/ln2): gram(Z) = 20*log2(e)*cos, so exp2(gram) = e^{20 cos}
#define ZSCALE 5.3715835f
#define NXCD 8

typedef __attribute__((ext_vector_type(8))) short bf16x8;
typedef __attribute__((ext_vector_type(4))) float f32x4;

#if __has_builtin(__builtin_amdgcn_exp2f)
#define EXP2F(x) __builtin_amdgcn_exp2f(x)
#else
#define EXP2F(x) exp2f(x)
#endif

// Z layout (fragment order): G-row R, element l stored at bf16 index
//   ( (R>>4)*128 + (l>>5)*64 + ((l>>3)&3)*16 + (R&15) )*8 + (l&7)
// MFMA fragment load for 16-row group g, K-chunk kc = contiguous 1 KB wave
// load Zf[g*128 + kc*64 + lane].
//
// HISTORY (keep):
//  - R9/R12: (256,5) spills. (256,4) is the occupancy ceiling.
//  - R10: __threadfence in all blocks -> L2 thrash, 5x slower.
//  - R11 (93.1us): 1 tile/block. R13 (91.8us): 2 ranks/block + prefetch.
//  - R14-R16: strip-mining / big unrolls fight compiler (scratch, spill).
//  - R17/R18 (107/101us): store+gather round-trip WORSE than atomics.
//  - R19 (98.2us): af1-reuse+swizzle: FETCH 89->11MB, dur unchanged ->
//    fragment traffic was never the stall.
//  - R20 (131.8us): barrier-free epilogue doubled atomics 2.1M->4.2M;
//    WRITE+FETCH 195MB == dur x BW. PROOF: tiles is atomic-coherence-bound,
//    linear in atomic count. part[] lines ping-pong across the 8
//    non-coherent XCD L2s via memory side; that movement IS the duration.
//  - R21 (this): per-XCD part replicas (8 x 2N floats, 512KB). Block reads
//    its physical XCD via s_getreg(HW_REG_XCC_ID) (HW-verified 0-7 on
//    MI355X) and atomics into its own replica -> no cross-XCD line sharing,
//    atomic lines stay in home L2, HBM traffic from atomics ~0. Swizzle
//    REMOVED: with replicas, scattering same-bi blocks across XCDs splits
//    each hot row-line into 8 parallel per-copy lines (swizzle would
//    re-serialize them on one XCD). Zn (2MB) fits every L2 regardless.
//    Epilogue: LDS-merged (low atomic count), af1-reuse, barrier-move.

__device__ __forceinline__ void unrank(int t, int& bi, int& bj) {
    int b = (int)((257.0f - sqrtf(66049.0f - 8.0f * (float)t)) * 0.5f);
    while (b * (257 - b) / 2 > t) --b;
    while ((b + 1) * (256 - b) / 2 <= t) ++b;
    bi = b;
    bj = b + (t - b * (257 - b) / 2);
}

// ---------------- Kernel 1: normalize -> scaled bf16 Z (fragment order),
//                  zero part8 (8*2N floats) / lacc / cnt ----------------
__global__ __launch_bounds__(256) void prep_kernel(
    const float* __restrict__ A, const float* __restrict__ P,
    __hip_bfloat16* __restrict__ Zn, float* __restrict__ diag20,
    float* __restrict__ part8, float* __restrict__ lacc, unsigned* __restrict__ cnt) {
    if (blockIdx.x < 512) part8[blockIdx.x * 256 + threadIdx.x] = 0.0f;
    else if (blockIdx.x == 512 && threadIdx.x == 0) { *lacc = 0.0f; *cnt = 0u; }

    const int lane = threadIdx.x & 63;   // element index l
    const int w    = threadIdx.x >> 6;
    const int r    = blockIdx.x * 4 + w; // A/P row
    const int u    = lane >> 3, sub = lane & 7;
    const int upos = (u >> 2) * 64 + (u & 3) * 16;   // kc*64 + q*16

    float a = A[r * D + lane];
    float p = P[r * D + lane];
    float sa = a * a, sp = p * p, dp = a * p;
    #pragma unroll
    for (int off = 1; off < 64; off <<= 1) {
        sa += __shfl_xor(sa, off, 64);
        sp += __shfl_xor(sp, off, 64);
        dp += __shfl_xor(dp, off, 64);
    }
    float na  = sqrtf(sa);
    float npn = sqrtf(sp);
    {   // A-row R = r
        int g = r >> 4, l2 = r & 15;
        Zn[(g * 128 + upos + l2) * 8 + sub] = __float2bfloat16(a * (ZSCALE / na));
    }
    {   // P-row R = N + r
        int R = N + r; int g = R >> 4, l2 = R & 15;
        Zn[(g * 128 + upos + l2) * 8 + sub] = __float2bfloat16(p * (ZSCALE / npn));
    }
    if (lane == 0)
        diag20[r] = (dp / fmaxf(na * npn, EPS)) * INVT;
}

// ---------------- Kernel 2: two triangular ranks per block, prefetched ------
__global__ __launch_bounds__(256, 4) void tiles_kernel(
    const __hip_bfloat16* __restrict__ Zn, float* __restrict__ part8) {
    __shared__ float rs[4][16][68];     // wave-local transpose; 2-way banks max
    __shared__ float merged[2][128];    // row merge over wc
    __shared__ float cmerged[2][2][64]; // col merge over wr: [wr][wc][col]

    const int tid = threadIdx.x;
    const int lane = tid & 63, w = tid >> 6;
    const int wr = w >> 1, wc = w & 1;
    const int ln = lane & 15, q = lane >> 4;
    const bf16x8* Zf = (const bf16x8*)Zn;

    // Physical XCD id -> private part replica (atomics never cross XCDs).
    unsigned xcc;
    asm volatile("s_getreg_b32 %0, hwreg(HW_REG_XCC_ID)" : "=s"(xcc));
    float* __restrict__ myp = part8 + (size_t)(xcc & (NXCD - 1)) * (2 * N);

    const int t0 = 2 * (int)blockIdx.x;
    const int t1 = t0 + 1;
    int bi0, bj0, bi1, bj1;
    unrank(t0, bi0, bj0);
    unrank(t1, bi1, bj1);

    const f32x4 zero = {0.0f, 0.0f, 0.0f, 0.0f};

    // ---------------- tile 0: load fragments ----------------
    bf16x8 af0[4][2], bv0[4][2];
    #pragma unroll
    for (int ii = 0; ii < 4; ++ii) {
        int ga = bi0 * 8 + wr * 4 + ii;
        int gb = bj0 * 8 + wc * 4 + ii;
        #pragma unroll
        for (int kc = 0; kc < 2; ++kc) {
            af0[ii][kc] = Zf[ga * 128 + kc * 64 + lane];
            bv0[ii][kc] = Zf[gb * 128 + kc * 64 + lane];
        }
    }

    // ---------------- tile 0: stripes (MFMA + exp) ----------------
    const bool dwave0 = (bi0 == bj0) && (wr == wc);
    float csum[4] = {0.0f, 0.0f, 0.0f, 0.0f};
    #pragma unroll
    for (int ii = 0; ii < 4; ++ii) {
        f32x4 acc[4];
        #pragma unroll
        for (int jj = 0; jj < 4; ++jj)
            acc[jj] = __builtin_amdgcn_mfma_f32_16x16x32_bf16(
                af0[ii][0], bv0[jj][0], zero, 0, 0, 0);
        #pragma unroll
        for (int jj = 0; jj < 4; ++jj)
            acc[jj] = __builtin_amdgcn_mfma_f32_16x16x32_bf16(
                af0[ii][1], bv0[jj][1], acc[jj], 0, 0, 0);

        f32x4 rsum_ii = {};
        #pragma unroll
        for (int jj = 0; jj < 4; ++jj) {
            f32x4 e;
            #pragma unroll
            for (int r = 0; r < 4; ++r) e[r] = EXP2F(acc[jj][r]);
            if (dwave0 && (ii == jj)) {
                #pragma unroll
                for (int r = 0; r < 4; ++r)
                    if (ln == q * 4 + r) e[r] = 0.0f;
            }
            rsum_ii += e;
            csum[jj] += (e[0] + e[1]) + (e[2] + e[3]);
        }
        *(f32x4*)&rs[w][ln][ii * 16 + q * 4] = rsum_ii;
    }

    // ---------------- prefetch tile 1 fragments ----------------
    // af reused when the pair stays in the same row block (4064/4128 pairs).
    bf16x8 af1[4][2], bv1[4][2];
    #pragma unroll
    for (int ii = 0; ii < 4; ++ii) {
        int gb = bj1 * 8 + wc * 4 + ii;
        #pragma unroll
        for (int kc = 0; kc < 2; ++kc)
            bv1[ii][kc] = Zf[gb * 128 + kc * 64 + lane];
    }
    if (bi1 == bi0) {
        #pragma unroll
        for (int ii = 0; ii < 4; ++ii) {
            af1[ii][0] = af0[ii][0];
            af1[ii][1] = af0[ii][1];
        }
    } else {
        #pragma unroll
        for (int ii = 0; ii < 4; ++ii) {
            int ga = bi1 * 8 + wr * 4 + ii;
            #pragma unroll
            for (int kc = 0; kc < 2; ++kc)
                af1[ii][kc] = Zf[ga * 128 + kc * 64 + lane];
        }
    }

    // ---------------- tile 0: reductions + atomics (XCD-local) --------------
    {
        float rowsum = 0.0f;
        #pragma unroll
        for (int l = 0; l < 16; ++l) rowsum += rs[w][l][lane];
        merged[wc][wr * 64 + lane] = rowsum;

        float cs0 = csum[0], cs1 = csum[1], cs2 = csum[2], cs3 = csum[3];
        cs0 += __shfl_xor(cs0, 16, 64); cs0 += __shfl_xor(cs0, 32, 64);
        cs1 += __shfl_xor(cs1, 16, 64); cs1 += __shfl_xor(cs1, 32, 64);
        cs2 += __shfl_xor(cs2, 16, 64); cs2 += __shfl_xor(cs2, 32, 64);
        cs3 += __shfl_xor(cs3, 16, 64); cs3 += __shfl_xor(cs3, 32, 64);
        float cval = (q == 0) ? cs0 : (q == 1) ? cs1 : (q == 2) ? cs2 : cs3;
        cmerged[wr][wc][q * 16 + ln] = cval;
        __syncthreads();

        if (tid < 128) {
            atomicAdd(myp + bi0 * 128 + tid, merged[0][tid] + merged[1][tid]);
        } else if (bi0 != bj0) {
            int col = tid - 128;
            atomicAdd(myp + bj0 * 128 + col,
                      cmerged[0][col >> 6][col & 63] + cmerged[1][col >> 6][col & 63]);
        }
    }
    // No barrier here (validated R18): tile-1 stripes only write per-wave
    // rs[w]; tile-0's merged/cmerged reads + atomics overlap the next
    // MFMA/exp phase. Barrier moved to after tile-1 stripes.

    // ---------------- tile 1: stripes (MFMA + exp) ----------------
    const bool dwave1 = (bi1 == bj1) && (wr == wc);
    float csumB[4] = {0.0f, 0.0f, 0.0f, 0.0f};
    #pragma unroll
    for (int ii = 0; ii < 4; ++ii) {
        f32x4 acc[4];
        #pragma unroll
        for (int jj = 0; jj < 4; ++jj)
            acc[jj] = __builtin_amdgcn_mfma_f32_16x16x32_bf16(
                af1[ii][0], bv1[jj][0], zero, 0, 0, 0);
        #pragma unroll
        for (int jj = 0; jj < 4; ++jj)
            acc[jj] = __builtin_amdgcn_mfma_f32_16x16x32_bf16(
                af1[ii][1], bv1[jj][1], acc[jj], 0, 0, 0);

        f32x4 rsum_ii = {};
        #pragma unroll
        for (int jj = 0; jj < 4; ++jj) {
            f32x4 e;
            #pragma unroll
            for (int r = 0; r < 4; ++r) e[r] = EXP2F(acc[jj][r]);
            if (dwave1 && (ii == jj)) {
                #pragma unroll
                for (int r = 0; r < 4; ++r)
                    if (ln == q * 4 + r) e[r] = 0.0f;
            }
            rsum_ii += e;
            csumB[jj] += (e[0] + e[1]) + (e[2] + e[3]);
        }
        *(f32x4*)&rs[w][ln][ii * 16 + q * 4] = rsum_ii;
    }

    __syncthreads();   // tile-0 merged/cmerged reads are done; safe to rewrite

    // ---------------- tile 1: reductions + atomics (XCD-local) --------------
    {
        float rowsum = 0.0f;
        #pragma unroll
        for (int l = 0; l < 16; ++l) rowsum += rs[w][l][lane];
        merged[wc][wr * 64 + lane] = rowsum;

        float cs0 = csumB[0], cs1 = csumB[1], cs2 = csumB[2], cs3 = csumB[3];
        cs0 += __shfl_xor(cs0, 16, 64); cs0 += __shfl_xor(cs0, 32, 64);
        cs1 += __shfl_xor(cs1, 16, 64); cs1 += __shfl_xor(cs1, 32, 64);
        cs2 += __shfl_xor(cs2, 16, 64); cs2 += __shfl_xor(cs2, 32, 64);
        cs3 += __shfl_xor(cs3, 16, 64); cs3 += __shfl_xor(cs3, 32, 64);
        float cval = (q == 0) ? cs0 : (q == 1) ? cs1 : (q == 2) ? cs2 : cs3;
        cmerged[wr][wc][q * 16 + ln] = cval;
        __syncthreads();

        if (tid < 128) {
            atomicAdd(myp + bi1 * 128 + tid, merged[0][tid] + merged[1][tid]);
        } else if (bi1 != bj1) {
            int col = tid - 128;
            atomicAdd(myp + bj1 * 128 + col,
                      cmerged[0][col >> 6][col & 63] + cmerged[1][col >> 6][col & 63]);
        }
    }
}

// ---------------- Kernel 3: gather replicas + per-row loss + finalize -------
__global__ __launch_bounds__(256) void loss_kernel(
    const float* __restrict__ part8, const float* __restrict__ diag20,
    float* __restrict__ lacc, unsigned* __restrict__ cnt, float* __restrict__ out) {
    int i = blockIdx.x * 256 + threadIdx.x;
    float s = 0.0f;
    #pragma unroll
    for (int x = 0; x < NXCD; ++x)
        s += part8[x * 2 * N + i] + part8[x * 2 * N + N + i];
    float v = logf(s) - diag20[i];
    #pragma unroll
    for (int off = 32; off > 0; off >>= 1) v += __shfl_down(v, off, 64);
    __shared__ float wsm[4];
    int lane = threadIdx.x & 63, wv = threadIdx.x >> 6;
    if (lane == 0) wsm[wv] = v;
    __syncthreads();
    if (threadIdx.x == 0) {
        atomicAdd(lacc, wsm[0] + wsm[1] + wsm[2] + wsm[3]);
        __threadfence();
        unsigned old = atomicAdd(cnt, 1u);
        if (old == (N / 256 - 1)) {
            float tot = atomicAdd(lacc, 0.0f);
            out[0] = tot * (1.0f / (float)N);
        }
    }
}

// ---------------- launch ----------------
extern "C" void kernel_launch(void* const* d_in, const int* in_sizes, int n_in,
                              void* d_out, int out_size, void* d_ws, size_t ws_size,
                              hipStream_t stream) {
    const float* A = (const float*)d_in[0];
    const float* P = (const float*)d_in[1];

    __hip_bfloat16* Zn = (__hip_bfloat16*)d_ws;                 // 2N*64 bf16 = 2 MiB
    float* diag20 = (float*)((char*)d_ws + 2u * N * D * sizeof(__hip_bfloat16));
    float* part8  = diag20 + N;          // 8 XCD replicas x 2N floats = 512 KB
    float* lacc   = part8 + NXCD * 2 * N;
    unsigned* cnt = (unsigned*)(lacc + 1);

    prep_kernel<<<N / 4, 256, 0, stream>>>(A, P, Zn, diag20, part8, lacc, cnt);

    const int nblocks = 128 * 129 / 4;   // 4128 blocks, 2 triangular ranks each
    tiles_kernel<<<nblocks, 256, 0, stream>>>(Zn, part8);

    loss_kernel<<<N / 256, 256, 0, stream>>>(part8, diag20, lacc, cnt,
                                             (float*)d_out);
}